// Round 1
// baseline (3085.209 us; speedup 1.0000x reference)
//
#include <hip/hip_runtime.h>

// Problem constants
#define B_ 8
#define N_ 2000
#define NH_ 30
#define C_ 16
#define D_ 480          // NH*C
#define L_ 8
#define K_ 4096
#define T1_ 6

#define BM 64
#define BN 96
#define BK 16

// ---------------------------------------------------------------------------
// Detect is_end storage format: 1 => 1-byte bool, 0 => int32.
// int32 storage of {0,1} guarantees bytes at (i%4!=0) are zero.
__global__ void k_flag(const unsigned char* __restrict__ raw, int* flag) {
    if (threadIdx.x == 0 && blockIdx.x == 0) {
        int f = 0;
        for (int i = 0; i < 4096; ++i) {
            if ((i & 3) != 0 && raw[i] != 0) { f = 1; break; }
        }
        *flag = f;
    }
}

// Zero sums + counts (must run every launch; harness does not re-poison ws)
__global__ void k_zero(float* __restrict__ sums, int* __restrict__ counts) {
    int stride = gridDim.x * blockDim.x;
    int i0 = blockIdx.x * blockDim.x + threadIdx.x;
    for (int i = i0; i < B_ * N_ * D_; i += stride) sums[i] = 0.f;
    for (int i = i0; i < B_ * N_; i += stride) counts[i] = 0;
}

// Expand is_end to int array + build per-segment end counts
__global__ void k_endcounts(const unsigned char* __restrict__ raw,
                            const int* __restrict__ flag,
                            const int* __restrict__ seg,
                            int* __restrict__ endi, int* __restrict__ counts) {
    int i = blockIdx.x * blockDim.x + threadIdx.x;
    if (i >= B_ * L_ * K_) return;
    int e = (*flag) ? (int)raw[i] : ((const int*)raw)[i];
    e = (e != 0) ? 1 : 0;
    endi[i] = e;
    if (e) {
        int b = i / (L_ * K_);
        atomicAdd(&counts[b * N_ + seg[i]], 1);
    }
}

// Level 0: z0 = feats[seg[0]]; scatter end rows into sums
__global__ __launch_bounds__(128)
void k_level0(const float* __restrict__ feats, const int* __restrict__ seg,
              const int* __restrict__ endi, float* __restrict__ z0,
              float* __restrict__ sums) {
    int bk = blockIdx.x;                 // 0..B*K-1
    int b = bk >> 12;                    // K=4096
    int k = bk & (K_ - 1);
    int sidx = (b * L_ + 0) * K_ + k;
    int n = seg[sidx];
    int e = endi[sidx];
    const float4* src = (const float4*)(feats + ((size_t)b * N_ + n) * D_);
    float4* dst = (float4*)(z0 + ((size_t)b * K_ + k) * D_);
    float* sm = sums + ((size_t)b * N_ + n) * D_;
    int t = threadIdx.x;
    if (t < D_ / 4) {
        float4 v = src[t];
        dst[t] = v;
        if (e) {
            atomicAdd(&sm[t * 4 + 0], v.x);
            atomicAdd(&sm[t * 4 + 1], v.y);
            atomicAdd(&sm[t * 4 + 2], v.z);
            atomicAdd(&sm[t * 4 + 3], v.w);
        }
    }
}

// Level l>=1: Z_l = diag(alpha) * (Z_{l-1}[par] @ W^T) + H_l, fused scatter.
// Grid: (K/BM, D/BN, B), block 256. Thread tile 4x6.
__global__ __launch_bounds__(256)
void k_level(const float* __restrict__ feats, const float* __restrict__ attn,
             const int* __restrict__ seg, const int* __restrict__ parent,
             const int* __restrict__ endi, const float* __restrict__ Wp,
             const float* __restrict__ zprev, float* __restrict__ zcur,
             float* __restrict__ sums, int l, int storez) {
    __shared__ float As[BM][BK + 4];   // +4 pad: bank spread, keeps 16B align
    __shared__ float Ws[BN][BK + 4];
    __shared__ float alpha_s[BM];
    __shared__ int par_s[BM], seg_s[BM], end_s[BM];

    int b = blockIdx.z;
    int k0 = blockIdx.x * BM;
    int d0 = blockIdx.y * BN;
    int tid = threadIdx.x;

    if (tid < BM) {
        int k = k0 + tid;
        int base = (b * L_ + l) * K_;
        int p = parent[base + k];
        int sk = seg[base + k];
        int ps = seg[base - K_ + p];        // parent's segment (level l-1)
        par_s[tid] = p;
        seg_s[tid] = sk;
        end_s[tid] = endi[base + k];
        alpha_s[tid] = attn[((size_t)b * N_ + ps) * N_ + sk];
    }
    __syncthreads();

    float acc[4][6];
#pragma unroll
    for (int i = 0; i < 4; ++i)
#pragma unroll
        for (int j = 0; j < 6; ++j) acc[i][j] = 0.f;

    int ty = tid >> 4;      // 0..15 -> rows ty*4..+3
    int tx = tid & 15;      // 0..15 -> cols tx*6..+5
    int arow = tid >> 2;    // 0..63
    int ae4 = (tid & 3) * 4;

    const float* zb = zprev + (size_t)b * K_ * D_;

    for (int e0 = 0; e0 < D_; e0 += BK) {
        // stage A: gathered rows of z_prev (256 float4s, one per thread)
        {
            const float* srow = zb + (size_t)par_s[arow] * D_ + e0 + ae4;
            *(float4*)&As[arow][ae4] = *(const float4*)srow;
        }
        // stage W: 96x16 = 384 float4s
        {
            int c = tid >> 2, e4 = (tid & 3) * 4;
            *(float4*)&Ws[c][e4] =
                *(const float4*)&Wp[(size_t)(d0 + c) * D_ + e0 + e4];
            int idx = tid + 256;
            if (idx < 384) {
                c = idx >> 2; e4 = (idx & 3) * 4;
                *(float4*)&Ws[c][e4] =
                    *(const float4*)&Wp[(size_t)(d0 + c) * D_ + e0 + e4];
            }
        }
        __syncthreads();
#pragma unroll
        for (int ee = 0; ee < BK; ee += 4) {
            float4 a0 = *(const float4*)&As[ty * 4 + 0][ee];
            float4 a1 = *(const float4*)&As[ty * 4 + 1][ee];
            float4 a2 = *(const float4*)&As[ty * 4 + 2][ee];
            float4 a3 = *(const float4*)&As[ty * 4 + 3][ee];
            float4 w0 = *(const float4*)&Ws[tx * 6 + 0][ee];
            float4 w1 = *(const float4*)&Ws[tx * 6 + 1][ee];
            float4 w2 = *(const float4*)&Ws[tx * 6 + 2][ee];
            float4 w3 = *(const float4*)&Ws[tx * 6 + 3][ee];
            float4 w4 = *(const float4*)&Ws[tx * 6 + 4][ee];
            float4 w5 = *(const float4*)&Ws[tx * 6 + 5][ee];
            float4 aa[4] = {a0, a1, a2, a3};
            float4 ww[6] = {w0, w1, w2, w3, w4, w5};
#pragma unroll
            for (int i = 0; i < 4; ++i)
#pragma unroll
                for (int j = 0; j < 6; ++j)
                    acc[i][j] += aa[i].x * ww[j].x + aa[i].y * ww[j].y +
                                 aa[i].z * ww[j].z + aa[i].w * ww[j].w;
        }
        __syncthreads();
    }

    // epilogue: z = alpha*acc + h; write zcur; scatter end rows
#pragma unroll
    for (int i = 0; i < 4; ++i) {
        int r = ty * 4 + i;
        int k = k0 + r;
        float al = alpha_s[r];
        int sk = seg_s[r];
        int en = end_s[r];
        const float* hrow = feats + ((size_t)b * N_ + sk) * D_ + d0 + tx * 6;
        float* zrow = zcur + ((size_t)b * K_ + k) * D_ + d0 + tx * 6;
        float* srow = sums + ((size_t)b * N_ + sk) * D_ + d0 + tx * 6;
#pragma unroll
        for (int j = 0; j < 6; ++j) {
            float v = al * acc[i][j] + hrow[j];
            if (storez) zrow[j] = v;
            if (en) atomicAdd(&srow[j], v);
        }
    }
}

// Final: mean, predictor head, mask. One wave per (b,n).
__global__ __launch_bounds__(64)
void k_final(const float* __restrict__ sums, const int* __restrict__ counts,
             const float* __restrict__ Wpred, const float* __restrict__ bpred,
             float* __restrict__ out) {
    int bn = blockIdx.x;                 // 0..B*N-1
    int cnt = counts[bn];
    float inv = 1.f / (float)(cnt > 1 ? cnt : 1);
    int lane = threadIdx.x;
    const float* srow = sums + (size_t)bn * D_;
    float* zout = out + (size_t)B_ * N_ * T1_ + (size_t)bn * D_;
    float part[T1_] = {0, 0, 0, 0, 0, 0};
    for (int d = lane; d < D_; d += 64) {
        float m = srow[d] * inv;
        zout[d] = m;
#pragma unroll
        for (int t = 0; t < T1_; ++t) part[t] += m * Wpred[t * D_ + d];
    }
#pragma unroll
    for (int t = 0; t < T1_; ++t) {
        float v = part[t];
        for (int off = 32; off; off >>= 1) v += __shfl_down(v, off);
        if (lane == 0)
            out[(size_t)bn * T1_ + t] = (cnt > 0) ? (v + bpred[t]) : 0.f;
    }
    if (lane == 0)
        out[(size_t)B_ * N_ * T1_ + (size_t)B_ * N_ * D_ + bn] =
            (cnt > 0) ? 1.f : 0.f;
}

extern "C" void kernel_launch(void* const* d_in, const int* in_sizes, int n_in,
                              void* d_out, int out_size, void* d_ws,
                              size_t ws_size, hipStream_t stream) {
    const float* feats = (const float*)d_in[0];   // [B,N,NH,C]
    const float* attn  = (const float*)d_in[1];   // [B,N,N]
    const int*   seg   = (const int*)d_in[2];     // [B,L,K]
    const int*   par   = (const int*)d_in[3];     // [B,L,K]
    const unsigned char* isend_raw = (const unsigned char*)d_in[4];
    const float* Wproj = (const float*)d_in[5];   // [D,D]
    const float* Wpred = (const float*)d_in[6];   // [T1,D]
    const float* bpred = (const float*)d_in[7];   // [T1]

    float* z0buf = (float*)d_ws;                        // B*K*D
    float* z1buf = z0buf + (size_t)B_ * K_ * D_;        // B*K*D
    float* sums  = z1buf + (size_t)B_ * K_ * D_;        // B*N*D
    int* counts  = (int*)(sums + (size_t)B_ * N_ * D_); // B*N
    int* endi    = counts + B_ * N_;                    // B*L*K
    int* flag    = endi + B_ * L_ * K_;                 // 1

    k_flag<<<1, 64, 0, stream>>>(isend_raw, flag);
    k_zero<<<1024, 256, 0, stream>>>(sums, counts);
    k_endcounts<<<(B_ * L_ * K_ + 255) / 256, 256, 0, stream>>>(
        isend_raw, flag, seg, endi, counts);
    k_level0<<<B_ * K_, 128, 0, stream>>>(feats, seg, endi, z0buf, sums);

    float* zp = z0buf;
    float* zc = z1buf;
    for (int l = 1; l < L_; ++l) {
        k_level<<<dim3(K_ / BM, D_ / BN, B_), 256, 0, stream>>>(
            feats, attn, seg, par, endi, Wproj, zp, zc, sums, l,
            (l < L_ - 1) ? 1 : 0);
        float* t = zp; zp = zc; zc = t;
    }

    k_final<<<B_ * N_, 64, 0, stream>>>(sums, counts, Wpred, bpred,
                                        (float*)d_out);
}

// Round 2
// 972.836 us; speedup vs baseline: 3.1714x; 3.1714x over previous
//
#include <hip/hip_runtime.h>

// Problem constants
#define B_ 8
#define N_ 2000
#define D_ 480          // NH*C = 30*16
#define L_ 8
#define K_ 4096
#define T1_ 6

#define BM 64
#define BN 96

typedef __attribute__((ext_vector_type(4))) float f32x4;
typedef __attribute__((ext_vector_type(8))) short bf16x8;

__device__ __forceinline__ unsigned short f2bf(float f) {
    unsigned int u = __builtin_bit_cast(unsigned int, f);
    u += 0x7fffu + ((u >> 16) & 1u);   // RNE
    return (unsigned short)(u >> 16);
}

// ---------------------------------------------------------------------------
// is_end storage sniff: 1 => 1-byte bool, 0 => int32 (bytes %4!=0 all zero).
__global__ void k_flag(const unsigned char* __restrict__ raw, int* flag) {
    if (threadIdx.x == 0 && blockIdx.x == 0) {
        int f = 0;
        for (int i = 0; i < 4096; ++i) {
            if ((i & 3) != 0 && raw[i] != 0) { f = 1; break; }
        }
        *flag = f;
    }
}

__global__ void k_zero(float* __restrict__ sums, int* __restrict__ counts) {
    int stride = gridDim.x * blockDim.x;
    int i0 = blockIdx.x * blockDim.x + threadIdx.x;
    for (int i = i0; i < B_ * N_ * D_; i += stride) sums[i] = 0.f;
    for (int i = i0; i < B_ * N_; i += stride) counts[i] = 0;
}

__global__ void k_wconv(const float* __restrict__ w,
                        unsigned short* __restrict__ wbf) {
    int i = blockIdx.x * blockDim.x + threadIdx.x;
    if (i < D_ * D_) wbf[i] = f2bf(w[i]);
}

__global__ void k_endcounts(const unsigned char* __restrict__ raw,
                            const int* __restrict__ flag,
                            const int* __restrict__ seg,
                            int* __restrict__ endi, int* __restrict__ counts) {
    int i = blockIdx.x * blockDim.x + threadIdx.x;
    if (i >= B_ * L_ * K_) return;
    int e = (*flag) ? (int)raw[i] : ((const int*)raw)[i];
    e = (e != 0) ? 1 : 0;
    endi[i] = e;
    if (e) {
        int b = i / (L_ * K_);
        atomicAdd(&counts[b * N_ + seg[i]], 1);
    }
}

// Level 0: z0_bf = bf16(feats[seg0]); scatter end rows (f32) into sums
__global__ __launch_bounds__(128)
void k_level0(const float* __restrict__ feats, const int* __restrict__ seg,
              const int* __restrict__ endi, unsigned short* __restrict__ z0,
              float* __restrict__ sums) {
    int bk = blockIdx.x;
    int b = bk >> 12;
    int k = bk & (K_ - 1);
    int sidx = (b * L_ + 0) * K_ + k;
    int n = seg[sidx];
    int e = endi[sidx];
    const float* src = feats + ((size_t)b * N_ + n) * D_;
    unsigned short* dst = z0 + ((size_t)b * K_ + k) * D_;
    float* sm = sums + ((size_t)b * N_ + n) * D_;
    int t = threadIdx.x;
    if (t < D_ / 4) {
        float4 v = *(const float4*)(src + t * 4);
        ushort4 o;
        o.x = f2bf(v.x); o.y = f2bf(v.y); o.z = f2bf(v.z); o.w = f2bf(v.w);
        *(ushort4*)(dst + t * 4) = o;
        if (e) {
            atomicAdd(&sm[t * 4 + 0], v.x);
            atomicAdd(&sm[t * 4 + 1], v.y);
            atomicAdd(&sm[t * 4 + 2], v.z);
            atomicAdd(&sm[t * 4 + 3], v.w);
        }
    }
}

// Level l>=1 via MFMA: Z_l = diag(alpha) * (Z_{l-1}[par] @ W^T) + H_l.
// Block 256 = 4 waves, tile BM=64 x BN=96; wave = 32 rows x 48 cols = 2x3
// fragments of 16x16x32 bf16. Operands loaded straight from L2/L3 (z_prev
// is 31.5 MB bf16 total, W is 0.46 MB) — no LDS GEMM staging.
__global__ __launch_bounds__(256)
void k_level_mfma(const float* __restrict__ feats,
                  const float* __restrict__ attn,
                  const int* __restrict__ seg, const int* __restrict__ parent,
                  const int* __restrict__ endi,
                  const unsigned short* __restrict__ wb,
                  const unsigned short* __restrict__ zprev,
                  unsigned short* __restrict__ zcur,
                  float* __restrict__ sums, int l, int storez) {
    __shared__ int par_s[BM], seg_s[BM], end_s[BM];
    __shared__ float alpha_s[BM];

    int b = blockIdx.z;
    int k0 = blockIdx.x * BM;
    int d0 = blockIdx.y * BN;
    int tid = threadIdx.x;

    if (tid < BM) {
        int base = (b * L_ + l) * K_;
        int p = parent[base + k0 + tid];
        int sk = seg[base + k0 + tid];
        int ps = seg[base - K_ + p];
        par_s[tid] = p;
        seg_s[tid] = sk;
        end_s[tid] = endi[base + k0 + tid];
        alpha_s[tid] = attn[((size_t)b * N_ + ps) * N_ + sk];
    }
    __syncthreads();

    int wave = tid >> 6, lane = tid & 63;
    int wr0 = (wave >> 1) * 32;       // 0 or 32
    int wc0 = (wave & 1) * 48;        // 0 or 48
    int laneRow = lane & 15;
    int laneK = (lane >> 4) * 8;

    const unsigned short* zb = zprev + (size_t)b * K_ * D_;
    // hoisted per-lane row base pointers
    const unsigned short* arow[2];
#pragma unroll
    for (int mi = 0; mi < 2; ++mi)
        arow[mi] = zb + (size_t)par_s[wr0 + mi * 16 + laneRow] * D_ + laneK;
    const unsigned short* brow[3];
#pragma unroll
    for (int ni = 0; ni < 3; ++ni)
        brow[ni] = wb + (size_t)(d0 + wc0 + ni * 16 + laneRow) * D_ + laneK;

    f32x4 acc[2][3];
#pragma unroll
    for (int mi = 0; mi < 2; ++mi)
#pragma unroll
        for (int ni = 0; ni < 3; ++ni) acc[mi][ni] = (f32x4)0.f;

    bf16x8 af[2], bfr[3];
#pragma unroll
    for (int mi = 0; mi < 2; ++mi) af[mi] = *(const bf16x8*)(arow[mi]);
#pragma unroll
    for (int ni = 0; ni < 3; ++ni) bfr[ni] = *(const bf16x8*)(brow[ni]);

#pragma unroll
    for (int e0 = 0; e0 < D_; e0 += 32) {
        bf16x8 an[2], bn[3];
        if (e0 + 32 < D_) {
#pragma unroll
            for (int mi = 0; mi < 2; ++mi)
                an[mi] = *(const bf16x8*)(arow[mi] + e0 + 32);
#pragma unroll
            for (int ni = 0; ni < 3; ++ni)
                bn[ni] = *(const bf16x8*)(brow[ni] + e0 + 32);
        }
#pragma unroll
        for (int mi = 0; mi < 2; ++mi)
#pragma unroll
            for (int ni = 0; ni < 3; ++ni)
                acc[mi][ni] = __builtin_amdgcn_mfma_f32_16x16x32_bf16(
                    af[mi], bfr[ni], acc[mi][ni], 0, 0, 0);
        if (e0 + 32 < D_) {
#pragma unroll
            for (int mi = 0; mi < 2; ++mi) af[mi] = an[mi];
#pragma unroll
            for (int ni = 0; ni < 3; ++ni) bfr[ni] = bn[ni];
        }
    }

    // epilogue: C layout col=lane&15, row=(lane>>4)*4+j
#pragma unroll
    for (int mi = 0; mi < 2; ++mi) {
#pragma unroll
        for (int j = 0; j < 4; ++j) {
            int rl = wr0 + mi * 16 + (lane >> 4) * 4 + j;
            int k = k0 + rl;
            float al = alpha_s[rl];
            int sk = seg_s[rl];
            int en = end_s[rl];
            const float* hrow = feats + ((size_t)b * N_ + sk) * D_;
            unsigned short* zrow = zcur + ((size_t)b * K_ + k) * D_;
            float* srow = sums + ((size_t)b * N_ + sk) * D_;
#pragma unroll
            for (int ni = 0; ni < 3; ++ni) {
                int c = d0 + wc0 + ni * 16 + (lane & 15);
                float v = al * acc[mi][ni][j] + hrow[c];
                if (storez) zrow[c] = f2bf(v);
                if (en) atomicAdd(&srow[c], v);
            }
        }
    }
}

// Final: mean, predictor head, mask. One wave per (b,n).
__global__ __launch_bounds__(64)
void k_final(const float* __restrict__ sums, const int* __restrict__ counts,
             const float* __restrict__ Wpred, const float* __restrict__ bpred,
             float* __restrict__ out) {
    int bn = blockIdx.x;
    int cnt = counts[bn];
    float inv = 1.f / (float)(cnt > 1 ? cnt : 1);
    int lane = threadIdx.x;
    const float* srow = sums + (size_t)bn * D_;
    float* zout = out + (size_t)B_ * N_ * T1_ + (size_t)bn * D_;
    float part[T1_] = {0, 0, 0, 0, 0, 0};
    for (int d = lane; d < D_; d += 64) {
        float m = srow[d] * inv;
        zout[d] = m;
#pragma unroll
        for (int t = 0; t < T1_; ++t) part[t] += m * Wpred[t * D_ + d];
    }
#pragma unroll
    for (int t = 0; t < T1_; ++t) {
        float v = part[t];
        for (int off = 32; off; off >>= 1) v += __shfl_down(v, off);
        if (lane == 0)
            out[(size_t)bn * T1_ + t] = (cnt > 0) ? (v + bpred[t]) : 0.f;
    }
    if (lane == 0)
        out[(size_t)B_ * N_ * T1_ + (size_t)B_ * N_ * D_ + bn] =
            (cnt > 0) ? 1.f : 0.f;
}

extern "C" void kernel_launch(void* const* d_in, const int* in_sizes, int n_in,
                              void* d_out, int out_size, void* d_ws,
                              size_t ws_size, hipStream_t stream) {
    const float* feats = (const float*)d_in[0];
    const float* attn  = (const float*)d_in[1];
    const int*   seg   = (const int*)d_in[2];
    const int*   par   = (const int*)d_in[3];
    const unsigned char* isend_raw = (const unsigned char*)d_in[4];
    const float* Wproj = (const float*)d_in[5];
    const float* Wpred = (const float*)d_in[6];
    const float* bpred = (const float*)d_in[7];

    // workspace layout (f32/int first, bf16 after)
    float* sums = (float*)d_ws;                          // B*N*D f32
    int* counts = (int*)(sums + (size_t)B_ * N_ * D_);   // B*N
    int* endi   = counts + B_ * N_;                      // B*L*K
    int* flag   = endi + B_ * L_ * K_;                   // 4 (pad)
    unsigned short* z0bf = (unsigned short*)(flag + 4);  // B*K*D bf16
    unsigned short* z1bf = z0bf + (size_t)B_ * K_ * D_;  // B*K*D bf16
    unsigned short* wbf  = z1bf + (size_t)B_ * K_ * D_;  // D*D bf16

    k_flag<<<1, 64, 0, stream>>>(isend_raw, flag);
    k_zero<<<1024, 256, 0, stream>>>(sums, counts);
    k_wconv<<<(D_ * D_ + 255) / 256, 256, 0, stream>>>(Wproj, wbf);
    k_endcounts<<<(B_ * L_ * K_ + 255) / 256, 256, 0, stream>>>(
        isend_raw, flag, seg, endi, counts);
    k_level0<<<B_ * K_, 128, 0, stream>>>(feats, seg, endi, z0bf, sums);

    unsigned short* zp = z0bf;
    unsigned short* zc = z1bf;
    for (int l = 1; l < L_; ++l) {
        k_level_mfma<<<dim3(K_ / BM, D_ / BN, B_), 256, 0, stream>>>(
            feats, attn, seg, par, endi, wbf, zp, zc, sums, l,
            (l < L_ - 1) ? 1 : 0);
        unsigned short* t = zp; zp = zc; zc = t;
    }

    k_final<<<B_ * N_, 64, 0, stream>>>(sums, counts, Wpred, bpred,
                                        (float*)d_out);
}

// Round 3
// 777.438 us; speedup vs baseline: 3.9684x; 1.2513x over previous
//
#include <hip/hip_runtime.h>

// Problem constants
#define B_ 8
#define N_ 2000
#define D_ 480          // NH*C = 30*16
#define L_ 8
#define K_ 4096
#define T1_ 6

#define BM 64
#define BN 96

typedef __attribute__((ext_vector_type(4))) float f32x4;
typedef __attribute__((ext_vector_type(8))) short bf16x8;

__device__ __forceinline__ unsigned short f2bf(float f) {
    unsigned int u = __builtin_bit_cast(unsigned int, f);
    u += 0x7fffu + ((u >> 16) & 1u);   // RNE
    return (unsigned short)(u >> 16);
}

// ---------------------------------------------------------------------------
// is_end storage sniff: 1 => 1-byte bool, 0 => int32 (bytes %4!=0 all zero).
// Parallel: 256 threads scan 4096 bytes; any nonzero byte at i%4!=0 => bool.
__global__ __launch_bounds__(256)
void k_flag(const unsigned char* __restrict__ raw, int* flag) {
    int t = threadIdx.x;
    if (t == 0) *flag = 0;
    __syncthreads();
    int any = 0;
    for (int i = t; i < 4096; i += 256) {
        if ((i & 3) != 0 && raw[i] != 0) any = 1;
    }
    if (__any(any) && (t & 63) == 0) atomicOr(flag, 1);
}

__global__ void k_zero(float* __restrict__ sums, int* __restrict__ counts) {
    int stride = gridDim.x * blockDim.x;
    int i0 = blockIdx.x * blockDim.x + threadIdx.x;
    for (int i = i0; i < B_ * N_ * D_; i += stride) sums[i] = 0.f;
    for (int i = i0; i < B_ * N_; i += stride) counts[i] = 0;
}

__global__ void k_wconv(const float* __restrict__ w,
                        unsigned short* __restrict__ wbf) {
    int i = blockIdx.x * blockDim.x + threadIdx.x;
    if (i < D_ * D_) wbf[i] = f2bf(w[i]);
}

__global__ void k_endcounts(const unsigned char* __restrict__ raw,
                            const int* __restrict__ flag,
                            const int* __restrict__ seg,
                            int* __restrict__ endi, int* __restrict__ counts) {
    int i = blockIdx.x * blockDim.x + threadIdx.x;
    if (i >= B_ * L_ * K_) return;
    int e = (*flag) ? (int)raw[i] : ((const int*)raw)[i];
    e = (e != 0) ? 1 : 0;
    endi[i] = e;
    if (e) {
        int b = i / (L_ * K_);
        atomicAdd(&counts[b * N_ + seg[i]], 1);
    }
}

// Level 0: z0_bf = bf16(feats[seg0]); scatter end rows (f32) into sums
__global__ __launch_bounds__(128)
void k_level0(const float* __restrict__ feats, const int* __restrict__ seg,
              const int* __restrict__ endi, unsigned short* __restrict__ z0,
              float* __restrict__ sums) {
    int bk = blockIdx.x;
    int b = bk >> 12;
    int k = bk & (K_ - 1);
    int sidx = (b * L_ + 0) * K_ + k;
    int n = seg[sidx];
    int e = endi[sidx];
    const float* src = feats + ((size_t)b * N_ + n) * D_;
    unsigned short* dst = z0 + ((size_t)b * K_ + k) * D_;
    float* sm = sums + ((size_t)b * N_ + n) * D_;
    int t = threadIdx.x;
    if (t < D_ / 4) {
        float4 v = *(const float4*)(src + t * 4);
        ushort4 o;
        o.x = f2bf(v.x); o.y = f2bf(v.y); o.z = f2bf(v.z); o.w = f2bf(v.w);
        *(ushort4*)(dst + t * 4) = o;
        if (e) {
            atomicAdd(&sm[t * 4 + 0], v.x);
            atomicAdd(&sm[t * 4 + 1], v.y);
            atomicAdd(&sm[t * 4 + 2], v.z);
            atomicAdd(&sm[t * 4 + 3], v.w);
        }
    }
}

// Level l>=1 via MFMA: Z_l = diag(alpha) * (Z_{l-1}[par] @ W^T) + H_l.
// Block 256 = 4 waves, tile BM=64 x BN=96; wave = 32 rows x 48 cols = 2x3
// fragments of 16x16x32 bf16. Operands loaded straight from L2/L3 (z_prev
// is 31.5 MB bf16 total, W is 0.46 MB) — no LDS GEMM staging.
__global__ __launch_bounds__(256)
void k_level_mfma(const float* __restrict__ feats,
                  const float* __restrict__ attn,
                  const int* __restrict__ seg, const int* __restrict__ parent,
                  const int* __restrict__ endi,
                  const unsigned short* __restrict__ wb,
                  const unsigned short* __restrict__ zprev,
                  unsigned short* __restrict__ zcur,
                  float* __restrict__ sums, int l, int storez) {
    __shared__ int par_s[BM], seg_s[BM], end_s[BM];
    __shared__ float alpha_s[BM];

    int b = blockIdx.z;
    int k0 = blockIdx.x * BM;
    int d0 = blockIdx.y * BN;
    int tid = threadIdx.x;

    if (tid < BM) {
        int base = (b * L_ + l) * K_;
        int p = parent[base + k0 + tid];
        int sk = seg[base + k0 + tid];
        int ps = seg[base - K_ + p];
        par_s[tid] = p;
        seg_s[tid] = sk;
        end_s[tid] = endi[base + k0 + tid];
        alpha_s[tid] = attn[((size_t)b * N_ + ps) * N_ + sk];
    }
    __syncthreads();

    int wave = tid >> 6, lane = tid & 63;
    int wr0 = (wave >> 1) * 32;       // 0 or 32
    int wc0 = (wave & 1) * 48;        // 0 or 48
    int laneRow = lane & 15;
    int laneK = (lane >> 4) * 8;

    const unsigned short* zb = zprev + (size_t)b * K_ * D_;
    // hoisted per-lane row base pointers
    const unsigned short* arow[2];
#pragma unroll
    for (int mi = 0; mi < 2; ++mi)
        arow[mi] = zb + (size_t)par_s[wr0 + mi * 16 + laneRow] * D_ + laneK;
    const unsigned short* brow[3];
#pragma unroll
    for (int ni = 0; ni < 3; ++ni)
        brow[ni] = wb + (size_t)(d0 + wc0 + ni * 16 + laneRow) * D_ + laneK;

    f32x4 acc[2][3];
#pragma unroll
    for (int mi = 0; mi < 2; ++mi)
#pragma unroll
        for (int ni = 0; ni < 3; ++ni) acc[mi][ni] = (f32x4)0.f;

    bf16x8 af[2], bfr[3];
#pragma unroll
    for (int mi = 0; mi < 2; ++mi) af[mi] = *(const bf16x8*)(arow[mi]);
#pragma unroll
    for (int ni = 0; ni < 3; ++ni) bfr[ni] = *(const bf16x8*)(brow[ni]);

#pragma unroll
    for (int e0 = 0; e0 < D_; e0 += 32) {
        bf16x8 an[2], bn[3];
        if (e0 + 32 < D_) {
#pragma unroll
            for (int mi = 0; mi < 2; ++mi)
                an[mi] = *(const bf16x8*)(arow[mi] + e0 + 32);
#pragma unroll
            for (int ni = 0; ni < 3; ++ni)
                bn[ni] = *(const bf16x8*)(brow[ni] + e0 + 32);
        }
#pragma unroll
        for (int mi = 0; mi < 2; ++mi)
#pragma unroll
            for (int ni = 0; ni < 3; ++ni)
                acc[mi][ni] = __builtin_amdgcn_mfma_f32_16x16x32_bf16(
                    af[mi], bfr[ni], acc[mi][ni], 0, 0, 0);
        if (e0 + 32 < D_) {
#pragma unroll
            for (int mi = 0; mi < 2; ++mi) af[mi] = an[mi];
#pragma unroll
            for (int ni = 0; ni < 3; ++ni) bfr[ni] = bn[ni];
        }
    }

    // epilogue: C layout col=lane&15, row=(lane>>4)*4+j
#pragma unroll
    for (int mi = 0; mi < 2; ++mi) {
#pragma unroll
        for (int j = 0; j < 4; ++j) {
            int rl = wr0 + mi * 16 + (lane >> 4) * 4 + j;
            int k = k0 + rl;
            float al = alpha_s[rl];
            int sk = seg_s[rl];
            int en = end_s[rl];
            const float* hrow = feats + ((size_t)b * N_ + sk) * D_;
            unsigned short* zrow = zcur + ((size_t)b * K_ + k) * D_;
            float* srow = sums + ((size_t)b * N_ + sk) * D_;
#pragma unroll
            for (int ni = 0; ni < 3; ++ni) {
                int c = d0 + wc0 + ni * 16 + (lane & 15);
                float v = al * acc[mi][ni][j] + hrow[c];
                if (storez) zrow[c] = f2bf(v);
                if (en) atomicAdd(&srow[c], v);
            }
        }
    }
}

// Final: mean, predictor head, mask. One wave per (b,n).
__global__ __launch_bounds__(64)
void k_final(const float* __restrict__ sums, const int* __restrict__ counts,
             const float* __restrict__ Wpred, const float* __restrict__ bpred,
             float* __restrict__ out) {
    int bn = blockIdx.x;
    int cnt = counts[bn];
    float inv = 1.f / (float)(cnt > 1 ? cnt : 1);
    int lane = threadIdx.x;
    const float* srow = sums + (size_t)bn * D_;
    float* zout = out + (size_t)B_ * N_ * T1_ + (size_t)bn * D_;
    float part[T1_] = {0, 0, 0, 0, 0, 0};
    for (int d = lane; d < D_; d += 64) {
        float m = srow[d] * inv;
        zout[d] = m;
#pragma unroll
        for (int t = 0; t < T1_; ++t) part[t] += m * Wpred[t * D_ + d];
    }
#pragma unroll
    for (int t = 0; t < T1_; ++t) {
        float v = part[t];
        for (int off = 32; off; off >>= 1) v += __shfl_down(v, off);
        if (lane == 0)
            out[(size_t)bn * T1_ + t] = (cnt > 0) ? (v + bpred[t]) : 0.f;
    }
    if (lane == 0)
        out[(size_t)B_ * N_ * T1_ + (size_t)B_ * N_ * D_ + bn] =
            (cnt > 0) ? 1.f : 0.f;
}

extern "C" void kernel_launch(void* const* d_in, const int* in_sizes, int n_in,
                              void* d_out, int out_size, void* d_ws,
                              size_t ws_size, hipStream_t stream) {
    const float* feats = (const float*)d_in[0];
    const float* attn  = (const float*)d_in[1];
    const int*   seg   = (const int*)d_in[2];
    const int*   par   = (const int*)d_in[3];
    const unsigned char* isend_raw = (const unsigned char*)d_in[4];
    const float* Wproj = (const float*)d_in[5];
    const float* Wpred = (const float*)d_in[6];
    const float* bpred = (const float*)d_in[7];

    // workspace layout (f32/int first, bf16 after)
    float* sums = (float*)d_ws;                          // B*N*D f32
    int* counts = (int*)(sums + (size_t)B_ * N_ * D_);   // B*N
    int* endi   = counts + B_ * N_;                      // B*L*K
    int* flag   = endi + B_ * L_ * K_;                   // 4 (pad)
    unsigned short* z0bf = (unsigned short*)(flag + 4);  // B*K*D bf16
    unsigned short* z1bf = z0bf + (size_t)B_ * K_ * D_;  // B*K*D bf16
    unsigned short* wbf  = z1bf + (size_t)B_ * K_ * D_;  // D*D bf16

    k_flag<<<1, 256, 0, stream>>>(isend_raw, flag);
    k_zero<<<1024, 256, 0, stream>>>(sums, counts);
    k_wconv<<<(D_ * D_ + 255) / 256, 256, 0, stream>>>(Wproj, wbf);
    k_endcounts<<<(B_ * L_ * K_ + 255) / 256, 256, 0, stream>>>(
        isend_raw, flag, seg, endi, counts);
    k_level0<<<B_ * K_, 128, 0, stream>>>(feats, seg, endi, z0bf, sums);

    unsigned short* zp = z0bf;
    unsigned short* zc = z1bf;
    for (int l = 1; l < L_; ++l) {
        k_level_mfma<<<dim3(K_ / BM, D_ / BN, B_), 256, 0, stream>>>(
            feats, attn, seg, par, endi, wbf, zp, zc, sums, l,
            (l < L_ - 1) ? 1 : 0);
        unsigned short* t = zp; zp = zc; zc = t;
    }

    k_final<<<B_ * N_, 64, 0, stream>>>(sums, counts, Wpred, bpred,
                                        (float*)d_out);
}

// Round 4
// 557.748 us; speedup vs baseline: 5.5316x; 1.3939x over previous
//
#include <hip/hip_runtime.h>

// Problem constants
#define B_ 8
#define N_ 2000
#define D_ 480          // NH*C = 30*16
#define L_ 8
#define K_ 4096
#define T1_ 6

#define BM 64
#define BN 96

typedef __attribute__((ext_vector_type(4))) float f32x4;
typedef __attribute__((ext_vector_type(8))) short bf16x8;

__device__ __forceinline__ unsigned short f2bf(float f) {
    unsigned int u = __builtin_bit_cast(unsigned int, f);
    u += 0x7fffu + ((u >> 16) & 1u);   // RNE
    return (unsigned short)(u >> 16);
}
__device__ __forceinline__ float bf2f(unsigned short u) {
    return __builtin_bit_cast(float, ((unsigned int)u) << 16);
}

// ---------------------------------------------------------------------------
// is_end storage sniff: 1 => 1-byte bool, 0 => int32 (bytes %4!=0 all zero).
__global__ __launch_bounds__(256)
void k_flag(const unsigned char* __restrict__ raw, int* flag) {
    int t = threadIdx.x;
    if (t == 0) *flag = 0;
    __syncthreads();
    int any = 0;
    for (int i = t; i < 4096; i += 256) {
        if ((i & 3) != 0 && raw[i] != 0) any = 1;
    }
    if (__any(any) && (t & 63) == 0) atomicOr(flag, 1);
}

__global__ void k_wconv(const float* __restrict__ w,
                        unsigned short* __restrict__ wbf) {
    int i = blockIdx.x * blockDim.x + threadIdx.x;
    if (i < D_ * D_) wbf[i] = f2bf(w[i]);
}

__global__ void k_feats2bf(const float* __restrict__ f,
                           unsigned short* __restrict__ o) {
    int i = blockIdx.x * blockDim.x + threadIdx.x;   // over float4s
    if (i < B_ * N_ * D_ / 4) {
        float4 v = ((const float4*)f)[i];
        ushort4 u;
        u.x = f2bf(v.x); u.y = f2bf(v.y); u.z = f2bf(v.z); u.w = f2bf(v.w);
        ((ushort4*)o)[i] = u;
    }
}

__global__ void k_zero_idx(int* __restrict__ counts, int* __restrict__ cursor) {
    int i = blockIdx.x * blockDim.x + threadIdx.x;
    if (i < B_ * N_) { counts[i] = 0; cursor[i] = 0; }
}

__global__ void k_endcounts(const unsigned char* __restrict__ raw,
                            const int* __restrict__ flag,
                            const int* __restrict__ seg,
                            int* __restrict__ endi, int* __restrict__ counts) {
    int i = blockIdx.x * blockDim.x + threadIdx.x;
    if (i >= B_ * L_ * K_) return;
    int e = (*flag) ? (int)raw[i] : ((const int*)raw)[i];
    e = (e != 0) ? 1 : 0;
    endi[i] = e;
    if (e) {
        int b = i / (L_ * K_);
        atomicAdd(&counts[b * N_ + seg[i]], 1);
    }
}

// offsets = exclusive prefix sum of counts (B*N entries -> B*N+1 offsets)
__global__ __launch_bounds__(256)
void k_scan(const int* __restrict__ counts, int* __restrict__ offsets) {
    __shared__ int part[256];
    const int CH = 63;                       // 256*63 = 16128 >= 16000
    int t = threadIdx.x;
    int s = 0;
    for (int j = 0; j < CH; ++j) {
        int i = t * CH + j;
        if (i < B_ * N_) s += counts[i];
    }
    part[t] = s;
    __syncthreads();
    if (t == 0) {
        int run = 0;
        for (int i = 0; i < 256; ++i) { int v = part[i]; part[i] = run; run += v; }
    }
    __syncthreads();
    int run = part[t];
    for (int j = 0; j < CH; ++j) {
        int i = t * CH + j;
        if (i < B_ * N_) { offsets[i] = run; run += counts[i]; }
    }
    if (t == 255) offsets[B_ * N_] = run;
}

// nodelist grouped by (b,n): entry = l*K + k  (l<8, K=4096 -> (l<<12)|k)
__global__ void k_build(const int* __restrict__ endi,
                        const int* __restrict__ seg,
                        const int* __restrict__ offsets,
                        int* __restrict__ cursor, int* __restrict__ nodelist) {
    int i = blockIdx.x * blockDim.x + threadIdx.x;   // over B*L*K
    if (i >= B_ * L_ * K_) return;
    if (!endi[i]) return;
    int b = i / (L_ * K_);
    int lk = i - b * (L_ * K_);                      // l*K + k
    int n = seg[i];
    int pos = atomicAdd(&cursor[b * N_ + n], 1);
    nodelist[offsets[b * N_ + n] + pos] = lk;
}

// Level l>=1 via MFMA: Z_l = diag(alpha) * (Z_{l-1}[gidx] @ W^T) + H_l.
// No scatter: z always stored (bf16). h read from bf16 feats.
// l==1: zprev = featsbf (prevRows=N), gather index = parent's segment id.
__global__ __launch_bounds__(256)
void k_level_mfma(const float* __restrict__ attn,
                  const int* __restrict__ seg, const int* __restrict__ parent,
                  const unsigned short* __restrict__ featsbf,
                  const unsigned short* __restrict__ wb,
                  const unsigned short* __restrict__ zprev,
                  unsigned short* __restrict__ zcur,
                  int l, int prevRows, int useps) {
    __shared__ int gidx_s[BM], seg_s[BM];
    __shared__ float alpha_s[BM];

    int b = blockIdx.z;
    int k0 = blockIdx.x * BM;
    int d0 = blockIdx.y * BN;
    int tid = threadIdx.x;

    if (tid < BM) {
        int base = (b * L_ + l) * K_;
        int p = parent[base + k0 + tid];
        int sk = seg[base + k0 + tid];
        int ps = seg[base - K_ + p];
        gidx_s[tid] = useps ? ps : p;
        seg_s[tid] = sk;
        alpha_s[tid] = attn[((size_t)b * N_ + ps) * N_ + sk];
    }
    __syncthreads();

    int wave = tid >> 6, lane = tid & 63;
    int wr0 = (wave >> 1) * 32;       // 0 or 32
    int wc0 = (wave & 1) * 48;        // 0 or 48
    int laneRow = lane & 15;
    int laneK = (lane >> 4) * 8;

    const unsigned short* zb = zprev + (size_t)b * prevRows * D_;
    const unsigned short* arow[2];
#pragma unroll
    for (int mi = 0; mi < 2; ++mi)
        arow[mi] = zb + (size_t)gidx_s[wr0 + mi * 16 + laneRow] * D_ + laneK;
    const unsigned short* brow[3];
#pragma unroll
    for (int ni = 0; ni < 3; ++ni)
        brow[ni] = wb + (size_t)(d0 + wc0 + ni * 16 + laneRow) * D_ + laneK;

    f32x4 acc[2][3];
#pragma unroll
    for (int mi = 0; mi < 2; ++mi)
#pragma unroll
        for (int ni = 0; ni < 3; ++ni) acc[mi][ni] = (f32x4)0.f;

    bf16x8 af[2], bfr[3];
#pragma unroll
    for (int mi = 0; mi < 2; ++mi) af[mi] = *(const bf16x8*)(arow[mi]);
#pragma unroll
    for (int ni = 0; ni < 3; ++ni) bfr[ni] = *(const bf16x8*)(brow[ni]);

#pragma unroll
    for (int e0 = 0; e0 < D_; e0 += 32) {
        bf16x8 an[2], bn[3];
        if (e0 + 32 < D_) {
#pragma unroll
            for (int mi = 0; mi < 2; ++mi)
                an[mi] = *(const bf16x8*)(arow[mi] + e0 + 32);
#pragma unroll
            for (int ni = 0; ni < 3; ++ni)
                bn[ni] = *(const bf16x8*)(brow[ni] + e0 + 32);
        }
#pragma unroll
        for (int mi = 0; mi < 2; ++mi)
#pragma unroll
            for (int ni = 0; ni < 3; ++ni)
                acc[mi][ni] = __builtin_amdgcn_mfma_f32_16x16x32_bf16(
                    af[mi], bfr[ni], acc[mi][ni], 0, 0, 0);
        if (e0 + 32 < D_) {
#pragma unroll
            for (int mi = 0; mi < 2; ++mi) af[mi] = an[mi];
#pragma unroll
            for (int ni = 0; ni < 3; ++ni) bfr[ni] = bn[ni];
        }
    }

    // epilogue: C layout col=lane&15, row=(lane>>4)*4+j
#pragma unroll
    for (int mi = 0; mi < 2; ++mi) {
#pragma unroll
        for (int j = 0; j < 4; ++j) {
            int rl = wr0 + mi * 16 + (lane >> 4) * 4 + j;
            int k = k0 + rl;
            float al = alpha_s[rl];
            int sk = seg_s[rl];
            const unsigned short* hrow = featsbf + ((size_t)b * N_ + sk) * D_;
            unsigned short* zrow = zcur + ((size_t)b * K_ + k) * D_;
#pragma unroll
            for (int ni = 0; ni < 3; ++ni) {
                int c = d0 + wc0 + ni * 16 + (lane & 15);
                float v = al * acc[mi][ni][j] + bf2f(hrow[c]);
                zrow[c] = f2bf(v);
            }
        }
    }
}

// Fused gather-reduce + mean + predictor + mask. One wave per (b,n).
__global__ __launch_bounds__(64)
void k_final_gather(const unsigned short* __restrict__ featsbf,
                    const unsigned short* __restrict__ zall,
                    const int* __restrict__ offsets,
                    const int* __restrict__ nodelist,
                    const float* __restrict__ Wpred,
                    const float* __restrict__ bpred, float* __restrict__ out) {
    int bn = blockIdx.x;
    int b = bn / N_;
    int s0 = offsets[bn], s1 = offsets[bn + 1];
    int cnt = s1 - s0;
    int lane = threadIdx.x;

    float acc[2][4] = {{0, 0, 0, 0}, {0, 0, 0, 0}};
    const unsigned short* ownrow = featsbf + (size_t)bn * D_;

    for (int s = s0; s < s1; ++s) {
        int e = nodelist[s];
        int l = e >> 12, k = e & (K_ - 1);
        const unsigned short* row =
            (l == 0) ? ownrow
                     : zall + (((size_t)(l - 1) * B_ + b) * K_ + k) * D_;
#pragma unroll
        for (int it = 0; it < 2; ++it) {
            int c4 = lane + 64 * it;
            if (c4 < D_ / 4) {
                ushort4 u = *(const ushort4*)(row + c4 * 4);
                acc[it][0] += bf2f(u.x);
                acc[it][1] += bf2f(u.y);
                acc[it][2] += bf2f(u.z);
                acc[it][3] += bf2f(u.w);
            }
        }
    }

    float inv = 1.f / (float)(cnt > 1 ? cnt : 1);
    float m[2][4];
#pragma unroll
    for (int it = 0; it < 2; ++it)
#pragma unroll
        for (int j = 0; j < 4; ++j) m[it][j] = acc[it][j] * inv;

    float* outz = out + (size_t)B_ * N_ * T1_ + (size_t)bn * D_;
#pragma unroll
    for (int it = 0; it < 2; ++it) {
        int c4 = lane + 64 * it;
        if (c4 < D_ / 4) {
            float4 v;
            v.x = m[it][0]; v.y = m[it][1]; v.z = m[it][2]; v.w = m[it][3];
            *(float4*)(outz + c4 * 4) = v;
        }
    }

    float part[T1_] = {0, 0, 0, 0, 0, 0};
#pragma unroll
    for (int it = 0; it < 2; ++it) {
        int c4 = lane + 64 * it;
        if (c4 < D_ / 4) {
#pragma unroll
            for (int t = 0; t < T1_; ++t)
#pragma unroll
                for (int j = 0; j < 4; ++j)
                    part[t] += m[it][j] * Wpred[t * D_ + c4 * 4 + j];
        }
    }
#pragma unroll
    for (int t = 0; t < T1_; ++t) {
        float v = part[t];
        for (int off = 32; off; off >>= 1) v += __shfl_down(v, off);
        if (lane == 0)
            out[(size_t)bn * T1_ + t] = (cnt > 0) ? (v + bpred[t]) : 0.f;
    }
    if (lane == 0)
        out[(size_t)B_ * N_ * T1_ + (size_t)B_ * N_ * D_ + bn] =
            (cnt > 0) ? 1.f : 0.f;
}

// ======================= fallback (atomic) path kernels =====================
__global__ void k_zero(float* __restrict__ sums, int* __restrict__ counts) {
    int stride = gridDim.x * blockDim.x;
    int i0 = blockIdx.x * blockDim.x + threadIdx.x;
    for (int i = i0; i < B_ * N_ * D_; i += stride) sums[i] = 0.f;
    for (int i = i0; i < B_ * N_; i += stride) counts[i] = 0;
}

__global__ __launch_bounds__(128)
void k_level0_at(const float* __restrict__ feats, const int* __restrict__ seg,
                 const int* __restrict__ endi, unsigned short* __restrict__ z0,
                 float* __restrict__ sums) {
    int bk = blockIdx.x;
    int b = bk >> 12;
    int k = bk & (K_ - 1);
    int sidx = (b * L_ + 0) * K_ + k;
    int n = seg[sidx];
    int e = endi[sidx];
    const float* src = feats + ((size_t)b * N_ + n) * D_;
    unsigned short* dst = z0 + ((size_t)b * K_ + k) * D_;
    float* sm = sums + ((size_t)b * N_ + n) * D_;
    int t = threadIdx.x;
    if (t < D_ / 4) {
        float4 v = *(const float4*)(src + t * 4);
        ushort4 o;
        o.x = f2bf(v.x); o.y = f2bf(v.y); o.z = f2bf(v.z); o.w = f2bf(v.w);
        *(ushort4*)(dst + t * 4) = o;
        if (e) {
            atomicAdd(&sm[t * 4 + 0], v.x);
            atomicAdd(&sm[t * 4 + 1], v.y);
            atomicAdd(&sm[t * 4 + 2], v.z);
            atomicAdd(&sm[t * 4 + 3], v.w);
        }
    }
}

__global__ __launch_bounds__(256)
void k_level_mfma_at(const float* __restrict__ feats,
                     const float* __restrict__ attn,
                     const int* __restrict__ seg, const int* __restrict__ parent,
                     const int* __restrict__ endi,
                     const unsigned short* __restrict__ wb,
                     const unsigned short* __restrict__ zprev,
                     unsigned short* __restrict__ zcur,
                     float* __restrict__ sums, int l, int storez) {
    __shared__ int par_s[BM], seg_s[BM], end_s[BM];
    __shared__ float alpha_s[BM];
    int b = blockIdx.z;
    int k0 = blockIdx.x * BM;
    int d0 = blockIdx.y * BN;
    int tid = threadIdx.x;
    if (tid < BM) {
        int base = (b * L_ + l) * K_;
        int p = parent[base + k0 + tid];
        int sk = seg[base + k0 + tid];
        int ps = seg[base - K_ + p];
        par_s[tid] = p; seg_s[tid] = sk;
        end_s[tid] = endi[base + k0 + tid];
        alpha_s[tid] = attn[((size_t)b * N_ + ps) * N_ + sk];
    }
    __syncthreads();
    int wave = tid >> 6, lane = tid & 63;
    int wr0 = (wave >> 1) * 32, wc0 = (wave & 1) * 48;
    int laneRow = lane & 15, laneK = (lane >> 4) * 8;
    const unsigned short* zb = zprev + (size_t)b * K_ * D_;
    const unsigned short* arow[2];
#pragma unroll
    for (int mi = 0; mi < 2; ++mi)
        arow[mi] = zb + (size_t)par_s[wr0 + mi * 16 + laneRow] * D_ + laneK;
    const unsigned short* brow[3];
#pragma unroll
    for (int ni = 0; ni < 3; ++ni)
        brow[ni] = wb + (size_t)(d0 + wc0 + ni * 16 + laneRow) * D_ + laneK;
    f32x4 acc[2][3];
#pragma unroll
    for (int mi = 0; mi < 2; ++mi)
#pragma unroll
        for (int ni = 0; ni < 3; ++ni) acc[mi][ni] = (f32x4)0.f;
    bf16x8 af[2], bfr[3];
#pragma unroll
    for (int mi = 0; mi < 2; ++mi) af[mi] = *(const bf16x8*)(arow[mi]);
#pragma unroll
    for (int ni = 0; ni < 3; ++ni) bfr[ni] = *(const bf16x8*)(brow[ni]);
#pragma unroll
    for (int e0 = 0; e0 < D_; e0 += 32) {
        bf16x8 an[2], bn[3];
        if (e0 + 32 < D_) {
#pragma unroll
            for (int mi = 0; mi < 2; ++mi) an[mi] = *(const bf16x8*)(arow[mi] + e0 + 32);
#pragma unroll
            for (int ni = 0; ni < 3; ++ni) bn[ni] = *(const bf16x8*)(brow[ni] + e0 + 32);
        }
#pragma unroll
        for (int mi = 0; mi < 2; ++mi)
#pragma unroll
            for (int ni = 0; ni < 3; ++ni)
                acc[mi][ni] = __builtin_amdgcn_mfma_f32_16x16x32_bf16(
                    af[mi], bfr[ni], acc[mi][ni], 0, 0, 0);
        if (e0 + 32 < D_) {
#pragma unroll
            for (int mi = 0; mi < 2; ++mi) af[mi] = an[mi];
#pragma unroll
            for (int ni = 0; ni < 3; ++ni) bfr[ni] = bn[ni];
        }
    }
#pragma unroll
    for (int mi = 0; mi < 2; ++mi) {
#pragma unroll
        for (int j = 0; j < 4; ++j) {
            int rl = wr0 + mi * 16 + (lane >> 4) * 4 + j;
            int k = k0 + rl;
            float al = alpha_s[rl];
            int sk = seg_s[rl];
            int en = end_s[rl];
            const float* hrow = feats + ((size_t)b * N_ + sk) * D_;
            unsigned short* zrow = zcur + ((size_t)b * K_ + k) * D_;
            float* srow = sums + ((size_t)b * N_ + sk) * D_;
#pragma unroll
            for (int ni = 0; ni < 3; ++ni) {
                int c = d0 + wc0 + ni * 16 + (lane & 15);
                float v = al * acc[mi][ni][j] + hrow[c];
                if (storez) zrow[c] = f2bf(v);
                if (en) atomicAdd(&srow[c], v);
            }
        }
    }
}

__global__ __launch_bounds__(64)
void k_final_at(const float* __restrict__ sums, const int* __restrict__ counts,
                const float* __restrict__ Wpred, const float* __restrict__ bpred,
                float* __restrict__ out) {
    int bn = blockIdx.x;
    int cnt = counts[bn];
    float inv = 1.f / (float)(cnt > 1 ? cnt : 1);
    int lane = threadIdx.x;
    const float* srow = sums + (size_t)bn * D_;
    float* zout = out + (size_t)B_ * N_ * T1_ + (size_t)bn * D_;
    float part[T1_] = {0, 0, 0, 0, 0, 0};
    for (int d = lane; d < D_; d += 64) {
        float mval = srow[d] * inv;
        zout[d] = mval;
#pragma unroll
        for (int t = 0; t < T1_; ++t) part[t] += mval * Wpred[t * D_ + d];
    }
#pragma unroll
    for (int t = 0; t < T1_; ++t) {
        float v = part[t];
        for (int off = 32; off; off >>= 1) v += __shfl_down(v, off);
        if (lane == 0)
            out[(size_t)bn * T1_ + t] = (cnt > 0) ? (v + bpred[t]) : 0.f;
    }
    if (lane == 0)
        out[(size_t)B_ * N_ * T1_ + (size_t)B_ * N_ * D_ + bn] =
            (cnt > 0) ? 1.f : 0.f;
}

// ===========================================================================
extern "C" void kernel_launch(void* const* d_in, const int* in_sizes, int n_in,
                              void* d_out, int out_size, void* d_ws,
                              size_t ws_size, hipStream_t stream) {
    const float* feats = (const float*)d_in[0];
    const float* attn  = (const float*)d_in[1];
    const int*   seg   = (const int*)d_in[2];
    const int*   par   = (const int*)d_in[3];
    const unsigned char* isend_raw = (const unsigned char*)d_in[4];
    const float* Wproj = (const float*)d_in[5];
    const float* Wpred = (const float*)d_in[6];
    const float* bpred = (const float*)d_in[7];

    char* p = (char*)d_ws;
    auto carve = [&p](size_t bytes) -> char* {
        char* r = p;
        p += (bytes + 255) & ~(size_t)255;
        return r;
    };

    // gather-path workspace
    size_t need = 0;
    {
        size_t q = 0;
        auto sz = [&q](size_t b) { q += (b + 255) & ~(size_t)255; };
        sz(B_ * N_ * 4);                    // counts
        sz(B_ * N_ * 4);                    // cursor
        sz((B_ * N_ + 1) * 4);              // offsets
        sz((size_t)B_ * L_ * K_ * 4);       // endi
        sz(16);                             // flag
        sz((size_t)B_ * L_ * K_ * 4);       // nodelist (worst case all end)
        sz((size_t)B_ * N_ * D_ * 2);       // featsbf
        sz((size_t)D_ * D_ * 2);            // wbf
        sz((size_t)(L_ - 1) * B_ * K_ * D_ * 2);  // zall: 7 slabs
        need = q;
    }

    if (ws_size >= need) {
        int* counts = (int*)carve(B_ * N_ * 4);
        int* cursor = (int*)carve(B_ * N_ * 4);
        int* offsets = (int*)carve((B_ * N_ + 1) * 4);
        int* endi = (int*)carve((size_t)B_ * L_ * K_ * 4);
        int* flag = (int*)carve(16);
        int* nodelist = (int*)carve((size_t)B_ * L_ * K_ * 4);
        unsigned short* featsbf = (unsigned short*)carve((size_t)B_ * N_ * D_ * 2);
        unsigned short* wbf = (unsigned short*)carve((size_t)D_ * D_ * 2);
        unsigned short* zall =
            (unsigned short*)carve((size_t)(L_ - 1) * B_ * K_ * D_ * 2);

        k_flag<<<1, 256, 0, stream>>>(isend_raw, flag);
        k_zero_idx<<<(B_ * N_ + 255) / 256, 256, 0, stream>>>(counts, cursor);
        k_wconv<<<(D_ * D_ + 255) / 256, 256, 0, stream>>>(Wproj, wbf);
        k_feats2bf<<<(B_ * N_ * D_ / 4 + 255) / 256, 256, 0, stream>>>(feats,
                                                                       featsbf);
        k_endcounts<<<(B_ * L_ * K_ + 255) / 256, 256, 0, stream>>>(
            isend_raw, flag, seg, endi, counts);
        k_scan<<<1, 256, 0, stream>>>(counts, offsets);
        k_build<<<(B_ * L_ * K_ + 255) / 256, 256, 0, stream>>>(
            endi, seg, offsets, cursor, nodelist);

        for (int l = 1; l < L_; ++l) {
            const unsigned short* zp =
                (l == 1) ? featsbf : zall + (size_t)(l - 2) * B_ * K_ * D_;
            unsigned short* zc = zall + (size_t)(l - 1) * B_ * K_ * D_;
            k_level_mfma<<<dim3(K_ / BM, D_ / BN, B_), 256, 0, stream>>>(
                attn, seg, par, featsbf, wbf, zp, zc, l,
                (l == 1) ? N_ : K_, (l == 1) ? 1 : 0);
        }

        k_final_gather<<<B_ * N_, 64, 0, stream>>>(
            featsbf, zall, offsets, nodelist, Wpred, bpred, (float*)d_out);
    } else {
        // fallback: round-3 atomic path
        float* sums = (float*)carve((size_t)B_ * N_ * D_ * 4);
        int* counts = (int*)carve(B_ * N_ * 4);
        int* endi = (int*)carve((size_t)B_ * L_ * K_ * 4);
        int* flag = (int*)carve(16);
        unsigned short* z0bf = (unsigned short*)carve((size_t)B_ * K_ * D_ * 2);
        unsigned short* z1bf = (unsigned short*)carve((size_t)B_ * K_ * D_ * 2);
        unsigned short* wbf = (unsigned short*)carve((size_t)D_ * D_ * 2);

        k_flag<<<1, 256, 0, stream>>>(isend_raw, flag);
        k_zero<<<1024, 256, 0, stream>>>(sums, counts);
        k_wconv<<<(D_ * D_ + 255) / 256, 256, 0, stream>>>(Wproj, wbf);
        k_endcounts<<<(B_ * L_ * K_ + 255) / 256, 256, 0, stream>>>(
            isend_raw, flag, seg, endi, counts);
        k_level0_at<<<B_ * K_, 128, 0, stream>>>(feats, seg, endi, z0bf, sums);
        unsigned short* zp = z0bf;
        unsigned short* zc = z1bf;
        for (int l = 1; l < L_; ++l) {
            k_level_mfma_at<<<dim3(K_ / BM, D_ / BN, B_), 256, 0, stream>>>(
                feats, attn, seg, par, endi, wbf, zp, zc, sums, l,
                (l < L_ - 1) ? 1 : 0);
            unsigned short* t = zp; zp = zc; zc = t;
        }
        k_final_at<<<B_ * N_, 64, 0, stream>>>(sums, counts, Wpred, bpred,
                                               (float*)d_out);
    }
}